// Round 7
// baseline (328.522 us; speedup 1.0000x reference)
//
#include <hip/hip_runtime.h>

#define HW 256
#define HP 258
#define BATCH 8
#define C 64
#define HO 244
#define NPAD 192
#define KTOT 576

typedef __bf16 bf16x8 __attribute__((ext_vector_type(8)));
typedef float f32x16 __attribute__((ext_vector_type(16)));
typedef unsigned short us8 __attribute__((ext_vector_type(8)));

__device__ inline unsigned short f2bf(float f) {
    union { float f; unsigned int u; } c; c.f = f;
    unsigned int lsb = (c.u >> 16) & 1;
    c.u += 0x7fffu + lsb;
    return (unsigned short)(c.u >> 16);
}

// ---------------- conv1: 1->64, fp32 math, writes bf16 NHWC into padded 258x258 ----
__global__ __launch_bounds__(256) void conv1_kernel(
    const float* __restrict__ x, const float* __restrict__ W1,
    const float* __restrict__ b1, unsigned short* __restrict__ h1p)
{
    int t = threadIdx.x;
    int p = blockIdx.x * 32 + (t >> 3);
    if (p >= BATCH * HP * HP) return;
    int b   = p / (HP * HP);
    int rem = p - b * HP * HP;
    int hp  = rem / HP;
    int wp  = rem - hp * HP;
    int cg  = (t & 7) * 8;
    size_t dst = (size_t)p * C + cg;

    if (hp == 0 || hp == HP - 1 || wp == 0 || wp == HP - 1) {
        *(uint4*)(h1p + dst) = make_uint4(0, 0, 0, 0);
        return;
    }
    int h = hp - 1, w = wp - 1;

    float v[9];
#pragma unroll
    for (int i = 0; i < 3; ++i)
#pragma unroll
        for (int j = 0; j < 3; ++j) {
            int hh = h + i - 1, ww = w + j - 1;
            bool ok = (hh >= 0) && (hh < HW) && (ww >= 0) && (ww < HW);
            v[i * 3 + j] = ok ? x[((size_t)b << 16) + hh * HW + ww] : 0.f;
        }

    unsigned short outv[8];
#pragma unroll
    for (int u = 0; u < 8; ++u) {
        int co = cg + u;
        float a = b1[co];
#pragma unroll
        for (int q = 0; q < 9; ++q) a += v[q] * W1[co * 9 + q];
        outv[u] = f2bf(fmaxf(a, 0.f));
    }
    *(uint4*)(h1p + dst) = *(uint4*)outv;
}

// ---- W2 repack, fragment-coalesced: B2r[((kstep*2+khalf)*64 + n)*8 + e] ----
__global__ __launch_bounds__(256) void repack_w2_kernel(
    const float* __restrict__ W2, unsigned short* __restrict__ Bg)
{
    int idx = blockIdx.x * 256 + threadIdx.x;
    if (idx >= 36 * 2 * C * 8) return;
    int e = idx & 7;
    int r = idx >> 3;
    int n = r & 63;
    int s = r >> 6;
    int khalf = s & 1;
    int kstep = s >> 1;
    int chunk = kstep >> 2, ks = kstep & 3;
    int ci = ks * 16 + khalf * 8 + e;
    Bg[idx] = f2bf(W2[((size_t)n * C + ci) * 9 + chunk]);
}

// ---- W3 repack, fragment-coalesced: B3r[((kstep*2+khalf)*192 + n)*8 + e] ----
__global__ __launch_bounds__(256) void repack_w3_kernel(
    const float* __restrict__ W3, unsigned short* __restrict__ Bg)
{
    int idx = blockIdx.x * 256 + threadIdx.x;
    if (idx >= 36 * 2 * NPAD * 8) return;
    int e = idx & 7;
    int r = idx >> 3;
    int n = r % NPAD;
    int s = r / NPAD;
    int khalf = s & 1;
    int kstep = s >> 1;
    int chunk = kstep >> 2, ks = kstep & 3;
    int ci = ks * 16 + khalf * 8 + e;
    float v = (n < 169) ? W3[((size_t)n * C + ci) * 9 + chunk] : 0.f;
    Bg[idx] = f2bf(v);
}

// ---------------- conv2: M=256 block, 4 waves of 64Mx64N, depth-1 B prefetch ----
// 256 threads; wave = m-slice (mrow_base = wave*64); full N=64 per wave.
// Ash stride 66 (2-way bank aliasing = free); 52.3 KB -> 3 blocks/CU.
__global__ __launch_bounds__(256, 3) void conv2_mfma_kernel(
    const unsigned short* __restrict__ h1p, const unsigned short* __restrict__ W2r,
    const float* __restrict__ b2, unsigned short* __restrict__ h2)
{
    __shared__ unsigned short Ash[396 * 66];   // 6 rows x 66 cols, ch-stride 66

    const int t = threadIdx.x;
    const int lane = t & 63;
    const int wave = t >> 6;
    const int b  = blockIdx.z;
    const int h0 = blockIdx.y * 4;
    const int w0 = blockIdx.x * 64;

    const int col   = lane & 31;
    const int khalf = lane >> 5;
    const int mrow_base = wave * 64;

    f32x16 acc[2][2];
#pragma unroll
    for (int ai = 0; ai < 2; ++ai)
#pragma unroll
        for (int nb = 0; nb < 2; ++nb)
#pragma unroll
            for (int r = 0; r < 16; ++r) acc[ai][nb][r] = 0.f;

    // stage full A-tile once: rows h0..h0+5 (padded), cols w0..w0+65
#pragma unroll
    for (int it = 0; it < 13; ++it) {
        int li = it * 256 + t;
        if (li < 396 * 8) {
            int p = li >> 3, g = li & 7;
            int row = p / 66, cl = p - row * 66;
            size_t src = (((size_t)b * HP + (h0 + row)) * HP + (w0 + cl)) * C + g * 8;
            *(uint4*)(Ash + p * 66 + g * 8) = *(const uint4*)(h1p + src);
        }
    }

    const unsigned short* bbase = W2r + ((size_t)khalf * C + col) * 8;
    us8 bc0 = *(const us8*)(bbase);
    us8 bc1 = *(const us8*)(bbase + 32 * 8);

    __syncthreads();

#pragma unroll
    for (int chunk = 0; chunk < 9; ++chunk) {
        const int ii = chunk / 3, jj = chunk - ii * 3;
        const int pixbase = (wave + ii) * 66 + jj;
#pragma unroll
        for (int ks = 0; ks < 4; ++ks) {
            const int kstep = chunk * 4 + ks;
            us8 bn0, bn1;
            if (kstep < 35) {
                const unsigned short* bp = bbase + (size_t)(kstep + 1) * (2 * C * 8);
                bn0 = *(const us8*)(bp);
                bn1 = *(const us8*)(bp + 32 * 8);
            }
            const int koff = ks * 16 + khalf * 8;
            bf16x8 a0 = __builtin_bit_cast(bf16x8, *(const us8*)(Ash + (pixbase + col) * 66 + koff));
            bf16x8 a1 = __builtin_bit_cast(bf16x8, *(const us8*)(Ash + (pixbase + col + 32) * 66 + koff));
            bf16x8 v0 = __builtin_bit_cast(bf16x8, bc0);
            bf16x8 v1 = __builtin_bit_cast(bf16x8, bc1);
            acc[0][0] = __builtin_amdgcn_mfma_f32_32x32x16_bf16(a0, v0, acc[0][0], 0, 0, 0);
            acc[0][1] = __builtin_amdgcn_mfma_f32_32x32x16_bf16(a0, v1, acc[0][1], 0, 0, 0);
            acc[1][0] = __builtin_amdgcn_mfma_f32_32x32x16_bf16(a1, v0, acc[1][0], 0, 0, 0);
            acc[1][1] = __builtin_amdgcn_mfma_f32_32x32x16_bf16(a1, v1, acc[1][1], 0, 0, 0);
            bc0 = bn0; bc1 = bn1;
        }
    }

#pragma unroll
    for (int nb = 0; nb < 2; ++nb) {
        const int n = nb * 32 + col;
        const float bias = b2[n];
#pragma unroll
        for (int ai = 0; ai < 2; ++ai) {
#pragma unroll
            for (int r = 0; r < 16; ++r) {
                int m = mrow_base + ai * 32 + (r & 3) + ((r >> 2) << 3) + (khalf << 2);
                int h = h0 + (m >> 6), w = w0 + (m & 63);
                float val = fmaxf(acc[ai][nb][r] + bias, 0.f);
                h2[(((size_t)b * HW + h) * HW + w) * C + n] = f2bf(val);
            }
        }
    }
}

// ---------------- conv3 + NLM: M=256 block, A-once, LDS x-tile epilogue ----------
// (unchanged from round 6)
__global__ __launch_bounds__(512, 3) void conv3_mfma_kernel(
    const float* __restrict__ x, const unsigned short* __restrict__ h2,
    const unsigned short* __restrict__ Bg, const float* __restrict__ b3,
    float* __restrict__ y)
{
    __shared__ unsigned short Ash[396 * 72];   // 57.0 KB
    __shared__ float Xsh[16 * 77];             // 4.9 KB
    __shared__ float red[8][64];               // 2.0 KB

    const int t = threadIdx.x;
    const int lane = t & 63;
    const int wave = t >> 6;
    const int b   = blockIdx.z;
    const int ho0 = blockIdx.y * 4;
    const int wo0 = blockIdx.x * 64;

    const int col   = lane & 31;
    const int khalf = lane >> 5;
    const int rsel      = wave >> 1;
    const int mrow_base = rsel * 64;
    const int nbase     = (wave & 1) * 96;

    f32x16 acc[2][3];
#pragma unroll
    for (int mi = 0; mi < 2; ++mi)
#pragma unroll
        for (int ni = 0; ni < 3; ++ni)
#pragma unroll
            for (int r = 0; r < 16; ++r) acc[mi][ni][r] = 0.f;

#pragma unroll
    for (int it = 0; it < 7; ++it) {
        int li = it * 512 + t;
        if (li < 396 * 8) {
            int p = li >> 3, g = li & 7;
            int row = p / 66, cl = p - row * 66;
            int ww = wo0 + 5 + cl; ww = ww < 255 ? ww : 255;
            size_t src = (((size_t)b * HW + (ho0 + 5 + row)) * HW + ww) * C + g * 8;
            *(uint4*)(Ash + p * 72 + g * 8) = *(const uint4*)(h2 + src);
        }
    }
    {
        const float* __restrict__ xplane = x + ((size_t)b << 16);
#pragma unroll
        for (int it = 0; it < 3; ++it) {
            int li = it * 512 + t;
            if (li < 16 * 76) {
                int rr = li / 76, cc = li - rr * 76;
                int ww = wo0 + cc; ww = ww < 255 ? ww : 255;
                Xsh[rr * 77 + cc] = xplane[(ho0 + rr) * HW + ww];
            }
        }
    }

    const unsigned short* bbase = Bg + ((size_t)khalf * NPAD + nbase + col) * 8;
    us8 bc0 = *(const us8*)(bbase);
    us8 bc1 = *(const us8*)(bbase + 32 * 8);
    us8 bc2 = *(const us8*)(bbase + 64 * 8);

    __syncthreads();

#pragma unroll
    for (int chunk = 0; chunk < 9; ++chunk) {
        const int ii = chunk / 3, jj = chunk - ii * 3;
        const int pixbase = (rsel + ii) * 66 + jj;
#pragma unroll
        for (int ks = 0; ks < 4; ++ks) {
            const int kstep = chunk * 4 + ks;
            us8 bn0, bn1, bn2;
            if (kstep < 35) {
                const unsigned short* bp = bbase + (size_t)(kstep + 1) * (2 * NPAD * 8);
                bn0 = *(const us8*)(bp);
                bn1 = *(const us8*)(bp + 32 * 8);
                bn2 = *(const us8*)(bp + 64 * 8);
            }
            const int koff = ks * 16 + khalf * 8;
            bf16x8 a0 = __builtin_bit_cast(bf16x8, *(const us8*)(Ash + (pixbase + col) * 72 + koff));
            bf16x8 a1 = __builtin_bit_cast(bf16x8, *(const us8*)(Ash + (pixbase + col + 32) * 72 + koff));
            bf16x8 v0 = __builtin_bit_cast(bf16x8, bc0);
            bf16x8 v1 = __builtin_bit_cast(bf16x8, bc1);
            bf16x8 v2 = __builtin_bit_cast(bf16x8, bc2);
            acc[0][0] = __builtin_amdgcn_mfma_f32_32x32x16_bf16(a0, v0, acc[0][0], 0, 0, 0);
            acc[0][1] = __builtin_amdgcn_mfma_f32_32x32x16_bf16(a0, v1, acc[0][1], 0, 0, 0);
            acc[0][2] = __builtin_amdgcn_mfma_f32_32x32x16_bf16(a0, v2, acc[0][2], 0, 0, 0);
            acc[1][0] = __builtin_amdgcn_mfma_f32_32x32x16_bf16(a1, v0, acc[1][0], 0, 0, 0);
            acc[1][1] = __builtin_amdgcn_mfma_f32_32x32x16_bf16(a1, v1, acc[1][1], 0, 0, 0);
            acc[1][2] = __builtin_amdgcn_mfma_f32_32x32x16_bf16(a1, v2, acc[1][2], 0, 0, 0);
            bc0 = bn0; bc1 = bn1; bc2 = bn2;
        }
    }

    int   qv[3], uo[3], vo[3];
    float b3v[3];
#pragma unroll
    for (int ni = 0; ni < 3; ++ni) {
        int q = nbase + ni * 32 + col;
        qv[ni] = q;
        int u = q / 13;
        uo[ni] = u;
        vo[ni] = q - u * 13;
        b3v[ni] = (q < 169) ? b3[q] : 0.f;
    }

    float partial[2][16];
#pragma unroll
    for (int mi = 0; mi < 2; ++mi)
#pragma unroll
        for (int r = 0; r < 16; ++r) {
            int mrow = mi * 32 + (r & 3) + ((r >> 2) << 3) + (khalf << 2);
            bool wok = (wo0 + mrow) < HO;
            float p = 0.f;
#pragma unroll
            for (int ni = 0; ni < 3; ++ni) {
                if (qv[ni] < 169 && wok) {
                    float s = acc[mi][ni][r] + b3v[ni];
                    p += s * Xsh[(rsel + uo[ni]) * 77 + mrow + vo[ni]];
                }
            }
            partial[mi][r] = p;
        }

#pragma unroll
    for (int mi = 0; mi < 2; ++mi)
#pragma unroll
        for (int r = 0; r < 16; ++r) {
            float p = partial[mi][r];
#pragma unroll
            for (int d = 1; d < 32; d <<= 1) p += __shfl_xor(p, d, 64);
            partial[mi][r] = p;
        }

    if (col == 0) {
#pragma unroll
        for (int mi = 0; mi < 2; ++mi)
#pragma unroll
            for (int r = 0; r < 16; ++r) {
                int mrow = mi * 32 + (r & 3) + ((r >> 2) << 3) + (khalf << 2);
                red[wave][mrow] = partial[mi][r];
            }
    }
    __syncthreads();

    if (t < 256) {
        int row_sel = t >> 6, m = t & 63;
        float val = red[row_sel * 2][m] + red[row_sel * 2 + 1][m];
        int wo = wo0 + m, ho = ho0 + row_sel;
        if (wo < HO)
            y[((size_t)b * HO + ho) * HO + wo] = val;
    }
}

extern "C" void kernel_launch(void* const* d_in, const int* in_sizes, int n_in,
                              void* d_out, int out_size, void* d_ws, size_t ws_size,
                              hipStream_t stream) {
    const float* x  = (const float*)d_in[0];
    const float* W1 = (const float*)d_in[1];
    const float* b1 = (const float*)d_in[2];
    const float* W2 = (const float*)d_in[3];
    const float* b2 = (const float*)d_in[4];
    const float* W3 = (const float*)d_in[5];
    const float* b3 = (const float*)d_in[6];
    float* out = (float*)d_out;

    unsigned short* h1p = (unsigned short*)d_ws;
    unsigned short* h2  = h1p + (size_t)BATCH * HP * HP * C;
    unsigned short* W2r = h2 + (size_t)BATCH * HW * HW * C;
    unsigned short* W3r = W2r + (size_t)36 * 2 * C * 8;

    repack_w2_kernel<<<144, 256, 0, stream>>>(W2, W2r);
    repack_w3_kernel<<<432, 256, 0, stream>>>(W3, W3r);
    conv1_kernel<<<(BATCH * HP * HP + 31) / 32, 256, 0, stream>>>(x, W1, b1, h1p);
    conv2_mfma_kernel<<<dim3(4, 64, 8), 256, 0, stream>>>(h1p, W2r, b2, h2);
    conv3_mfma_kernel<<<dim3(4, 61, 8), 512, 0, stream>>>(x, h2, W3r, b3, out);
}

// Round 8
// 252.381 us; speedup vs baseline: 1.3017x; 1.3017x over previous
//
#include <hip/hip_runtime.h>

#define HW 256
#define BATCH 8
#define C 64
#define HO 244
#define NPAD 192
#define KTOT 576

typedef __bf16 bf16x8 __attribute__((ext_vector_type(8)));
typedef float f32x16 __attribute__((ext_vector_type(16)));
typedef unsigned short us8 __attribute__((ext_vector_type(8)));

__device__ inline unsigned short f2bf(float f) {
    union { float f; unsigned int u; } c; c.f = f;
    unsigned int lsb = (c.u >> 16) & 1;
    c.u += 0x7fffu + lsb;
    return (unsigned short)(c.u >> 16);
}

// ---- merged W2+W3 repack, fragment-coalesced: [((kstep*2+khalf)*N + n)*8 + e] ----
__global__ __launch_bounds__(256) void repack_w_kernel(
    const float* __restrict__ W2, const float* __restrict__ W3,
    unsigned short* __restrict__ B2g, unsigned short* __restrict__ B3g)
{
    int idx = blockIdx.x * 256 + threadIdx.x;
    if (idx < 36 * 2 * C * 8) {
        int e = idx & 7;
        int r = idx >> 3;
        int n = r & 63;
        int s = r >> 6;
        int khalf = s & 1;
        int kstep = s >> 1;
        int chunk = kstep >> 2, ks = kstep & 3;
        int ci = ks * 16 + khalf * 8 + e;
        B2g[idx] = f2bf(W2[((size_t)n * C + ci) * 9 + chunk]);
    } else {
        int j = idx - 36 * 2 * C * 8;
        if (j >= 36 * 2 * NPAD * 8) return;
        int e = j & 7;
        int r = j >> 3;
        int n = r % NPAD;
        int s = r / NPAD;
        int khalf = s & 1;
        int kstep = s >> 1;
        int chunk = kstep >> 2, ks = kstep & 3;
        int ci = ks * 16 + khalf * 8 + e;
        float v = (n < 169) ? W3[((size_t)n * C + ci) * 9 + chunk] : 0.f;
        B3g[j] = f2bf(v);
    }
}

// ---------------- fused conv1+conv2: h1 tile computed in-block, then MFMA ------
// M=256 block (4 rows x 64 w), 4 waves of 64Mx64N, depth-1 B prefetch.
// Ash = h1 tile, 6 rows x 66 cols x 64ch bf16, per-pixel stride 66 (52,272 B).
// Xsh = x tile, 8 rows x 68 cols fp32 (2,176 B).  Total 54,448 B -> 3 blocks/CU.
__global__ __launch_bounds__(256, 3) void conv2_fused_kernel(
    const float* __restrict__ x, const float* __restrict__ W1,
    const float* __restrict__ b1, const unsigned short* __restrict__ W2r,
    const float* __restrict__ b2, unsigned short* __restrict__ h2)
{
    __shared__ unsigned short Ash[396 * 66];
    __shared__ float Xsh[8 * 68];

    const int t = threadIdx.x;
    const int lane = t & 63;
    const int wave = t >> 6;
    const int b  = blockIdx.z;
    const int h0 = blockIdx.y * 4;
    const int w0 = blockIdx.x * 64;

    const int col   = lane & 31;
    const int khalf = lane >> 5;
    const int mrow_base = wave * 64;

    // ---- stage x tile: rows h0-2..h0+5, cols w0-2..w0+65, zero OOB ----
    const float* __restrict__ xplane = x + ((size_t)b << 16);
#pragma unroll
    for (int it = 0; it < 3; ++it) {
        int li = it * 256 + t;
        if (li < 8 * 68) {
            int rr = li / 68, cc = li - rr * 68;
            int hh = h0 - 2 + rr, ww = w0 - 2 + cc;
            bool ok = (hh >= 0) && (hh < HW) && (ww >= 0) && (ww < HW);
            Xsh[li] = ok ? xplane[hh * HW + ww] : 0.f;
        }
    }

    // hoist this thread's W1 channel-group (g fixed: li&7 == t&7 for all iters)
    const int g = t & 7;
    float w1r[72], b1r[8];
#pragma unroll
    for (int u = 0; u < 8; ++u) {
        b1r[u] = b1[g * 8 + u];
#pragma unroll
        for (int q = 0; q < 9; ++q)
            w1r[u * 9 + q] = W1[(g * 8 + u) * 9 + q];
    }

    __syncthreads();   // Xsh ready

    // ---- compute h1 tile (conv1 + ReLU + bf16) into Ash ----
    // unit li = (pixel p)*8 + g over 396*8 = 3168
#pragma unroll
    for (int it = 0; it < 13; ++it) {
        int li = it * 256 + t;
        if (li < 3168) {
            int p = li >> 3;
            int pr = p / 66, pc = p - pr * 66;
            int hh = h0 - 1 + pr, ww = w0 - 1 + pc;
            unsigned short ov[8];
            if (hh >= 0 && hh < HW && ww >= 0 && ww < HW) {
                float xv[9];
#pragma unroll
                for (int i = 0; i < 3; ++i)
#pragma unroll
                    for (int j = 0; j < 3; ++j)
                        xv[i * 3 + j] = Xsh[(pr + i) * 68 + (pc + j)];
#pragma unroll
                for (int u = 0; u < 8; ++u) {
                    float a = b1r[u];
#pragma unroll
                    for (int q = 0; q < 9; ++q) a += xv[q] * w1r[u * 9 + q];
                    ov[u] = f2bf(fmaxf(a, 0.f));
                }
            } else {
#pragma unroll
                for (int u = 0; u < 8; ++u) ov[u] = 0;
            }
            *(uint4*)(Ash + p * 66 + g * 8) = *(uint4*)ov;
        }
    }

    // ---- B preload (chunk 0) before the barrier ----
    const unsigned short* bbase = W2r + ((size_t)khalf * C + col) * 8;
    us8 bc0 = *(const us8*)(bbase);
    us8 bc1 = *(const us8*)(bbase + 32 * 8);

    f32x16 acc[2][2];
#pragma unroll
    for (int ai = 0; ai < 2; ++ai)
#pragma unroll
        for (int nb = 0; nb < 2; ++nb)
#pragma unroll
            for (int r = 0; r < 16; ++r) acc[ai][nb][r] = 0.f;

    __syncthreads();   // Ash ready

#pragma unroll
    for (int chunk = 0; chunk < 9; ++chunk) {
        const int ii = chunk / 3, jj = chunk - ii * 3;
        const int pixbase = (wave + ii) * 66 + jj;
#pragma unroll
        for (int ks = 0; ks < 4; ++ks) {
            const int kstep = chunk * 4 + ks;
            us8 bn0, bn1;
            if (kstep < 35) {
                const unsigned short* bp = bbase + (size_t)(kstep + 1) * (2 * C * 8);
                bn0 = *(const us8*)(bp);
                bn1 = *(const us8*)(bp + 32 * 8);
            }
            const int koff = ks * 16 + khalf * 8;
            bf16x8 a0 = __builtin_bit_cast(bf16x8, *(const us8*)(Ash + (pixbase + col) * 66 + koff));
            bf16x8 a1 = __builtin_bit_cast(bf16x8, *(const us8*)(Ash + (pixbase + col + 32) * 66 + koff));
            bf16x8 v0 = __builtin_bit_cast(bf16x8, bc0);
            bf16x8 v1 = __builtin_bit_cast(bf16x8, bc1);
            acc[0][0] = __builtin_amdgcn_mfma_f32_32x32x16_bf16(a0, v0, acc[0][0], 0, 0, 0);
            acc[0][1] = __builtin_amdgcn_mfma_f32_32x32x16_bf16(a0, v1, acc[0][1], 0, 0, 0);
            acc[1][0] = __builtin_amdgcn_mfma_f32_32x32x16_bf16(a1, v0, acc[1][0], 0, 0, 0);
            acc[1][1] = __builtin_amdgcn_mfma_f32_32x32x16_bf16(a1, v1, acc[1][1], 0, 0, 0);
            bc0 = bn0; bc1 = bn1;
        }
    }

#pragma unroll
    for (int nb = 0; nb < 2; ++nb) {
        const int n = nb * 32 + col;
        const float bias = b2[n];
#pragma unroll
        for (int ai = 0; ai < 2; ++ai) {
#pragma unroll
            for (int r = 0; r < 16; ++r) {
                int m = mrow_base + ai * 32 + (r & 3) + ((r >> 2) << 3) + (khalf << 2);
                int h = h0 + (m >> 6), w = w0 + (m & 63);
                float val = fmaxf(acc[ai][nb][r] + bias, 0.f);
                h2[(((size_t)b * HW + h) * HW + w) * C + n] = f2bf(val);
            }
        }
    }
}

// ---------------- conv3 + NLM: M=256 block, A-once, LDS x-tile epilogue ----------
// (unchanged from round 6/7)
__global__ __launch_bounds__(512, 3) void conv3_mfma_kernel(
    const float* __restrict__ x, const unsigned short* __restrict__ h2,
    const unsigned short* __restrict__ Bg, const float* __restrict__ b3,
    float* __restrict__ y)
{
    __shared__ unsigned short Ash[396 * 72];
    __shared__ float Xsh[16 * 77];
    __shared__ float red[8][64];

    const int t = threadIdx.x;
    const int lane = t & 63;
    const int wave = t >> 6;
    const int b   = blockIdx.z;
    const int ho0 = blockIdx.y * 4;
    const int wo0 = blockIdx.x * 64;

    const int col   = lane & 31;
    const int khalf = lane >> 5;
    const int rsel      = wave >> 1;
    const int mrow_base = rsel * 64;
    const int nbase     = (wave & 1) * 96;

    f32x16 acc[2][3];
#pragma unroll
    for (int mi = 0; mi < 2; ++mi)
#pragma unroll
        for (int ni = 0; ni < 3; ++ni)
#pragma unroll
            for (int r = 0; r < 16; ++r) acc[mi][ni][r] = 0.f;

#pragma unroll
    for (int it = 0; it < 7; ++it) {
        int li = it * 512 + t;
        if (li < 396 * 8) {
            int p = li >> 3, g = li & 7;
            int row = p / 66, cl = p - row * 66;
            int ww = wo0 + 5 + cl; ww = ww < 255 ? ww : 255;
            size_t src = (((size_t)b * HW + (ho0 + 5 + row)) * HW + ww) * C + g * 8;
            *(uint4*)(Ash + p * 72 + g * 8) = *(const uint4*)(h2 + src);
        }
    }
    {
        const float* __restrict__ xplane = x + ((size_t)b << 16);
#pragma unroll
        for (int it = 0; it < 3; ++it) {
            int li = it * 512 + t;
            if (li < 16 * 76) {
                int rr = li / 76, cc = li - rr * 76;
                int ww = wo0 + cc; ww = ww < 255 ? ww : 255;
                Xsh[rr * 77 + cc] = xplane[(ho0 + rr) * HW + ww];
            }
        }
    }

    const unsigned short* bbase = Bg + ((size_t)khalf * NPAD + nbase + col) * 8;
    us8 bc0 = *(const us8*)(bbase);
    us8 bc1 = *(const us8*)(bbase + 32 * 8);
    us8 bc2 = *(const us8*)(bbase + 64 * 8);

    __syncthreads();

#pragma unroll
    for (int chunk = 0; chunk < 9; ++chunk) {
        const int ii = chunk / 3, jj = chunk - ii * 3;
        const int pixbase = (rsel + ii) * 66 + jj;
#pragma unroll
        for (int ks = 0; ks < 4; ++ks) {
            const int kstep = chunk * 4 + ks;
            us8 bn0, bn1, bn2;
            if (kstep < 35) {
                const unsigned short* bp = bbase + (size_t)(kstep + 1) * (2 * NPAD * 8);
                bn0 = *(const us8*)(bp);
                bn1 = *(const us8*)(bp + 32 * 8);
                bn2 = *(const us8*)(bp + 64 * 8);
            }
            const int koff = ks * 16 + khalf * 8;
            bf16x8 a0 = __builtin_bit_cast(bf16x8, *(const us8*)(Ash + (pixbase + col) * 72 + koff));
            bf16x8 a1 = __builtin_bit_cast(bf16x8, *(const us8*)(Ash + (pixbase + col + 32) * 72 + koff));
            bf16x8 v0 = __builtin_bit_cast(bf16x8, bc0);
            bf16x8 v1 = __builtin_bit_cast(bf16x8, bc1);
            bf16x8 v2 = __builtin_bit_cast(bf16x8, bc2);
            acc[0][0] = __builtin_amdgcn_mfma_f32_32x32x16_bf16(a0, v0, acc[0][0], 0, 0, 0);
            acc[0][1] = __builtin_amdgcn_mfma_f32_32x32x16_bf16(a0, v1, acc[0][1], 0, 0, 0);
            acc[0][2] = __builtin_amdgcn_mfma_f32_32x32x16_bf16(a0, v2, acc[0][2], 0, 0, 0);
            acc[1][0] = __builtin_amdgcn_mfma_f32_32x32x16_bf16(a1, v0, acc[1][0], 0, 0, 0);
            acc[1][1] = __builtin_amdgcn_mfma_f32_32x32x16_bf16(a1, v1, acc[1][1], 0, 0, 0);
            acc[1][2] = __builtin_amdgcn_mfma_f32_32x32x16_bf16(a1, v2, acc[1][2], 0, 0, 0);
            bc0 = bn0; bc1 = bn1; bc2 = bn2;
        }
    }

    int   qv[3], uo[3], vo[3];
    float b3v[3];
#pragma unroll
    for (int ni = 0; ni < 3; ++ni) {
        int q = nbase + ni * 32 + col;
        qv[ni] = q;
        int u = q / 13;
        uo[ni] = u;
        vo[ni] = q - u * 13;
        b3v[ni] = (q < 169) ? b3[q] : 0.f;
    }

    float partial[2][16];
#pragma unroll
    for (int mi = 0; mi < 2; ++mi)
#pragma unroll
        for (int r = 0; r < 16; ++r) {
            int mrow = mi * 32 + (r & 3) + ((r >> 2) << 3) + (khalf << 2);
            bool wok = (wo0 + mrow) < HO;
            float p = 0.f;
#pragma unroll
            for (int ni = 0; ni < 3; ++ni) {
                if (qv[ni] < 169 && wok) {
                    float s = acc[mi][ni][r] + b3v[ni];
                    p += s * Xsh[(rsel + uo[ni]) * 77 + mrow + vo[ni]];
                }
            }
            partial[mi][r] = p;
        }

#pragma unroll
    for (int mi = 0; mi < 2; ++mi)
#pragma unroll
        for (int r = 0; r < 16; ++r) {
            float p = partial[mi][r];
#pragma unroll
            for (int d = 1; d < 32; d <<= 1) p += __shfl_xor(p, d, 64);
            partial[mi][r] = p;
        }

    if (col == 0) {
#pragma unroll
        for (int mi = 0; mi < 2; ++mi)
#pragma unroll
            for (int r = 0; r < 16; ++r) {
                int mrow = mi * 32 + (r & 3) + ((r >> 2) << 3) + (khalf << 2);
                red[wave][mrow] = partial[mi][r];
            }
    }
    __syncthreads();

    if (t < 256) {
        int row_sel = t >> 6, m = t & 63;
        float val = red[row_sel * 2][m] + red[row_sel * 2 + 1][m];
        int wo = wo0 + m, ho = ho0 + row_sel;
        if (wo < HO)
            y[((size_t)b * HO + ho) * HO + wo] = val;
    }
}

extern "C" void kernel_launch(void* const* d_in, const int* in_sizes, int n_in,
                              void* d_out, int out_size, void* d_ws, size_t ws_size,
                              hipStream_t stream) {
    const float* x  = (const float*)d_in[0];
    const float* W1 = (const float*)d_in[1];
    const float* b1 = (const float*)d_in[2];
    const float* W2 = (const float*)d_in[3];
    const float* b2 = (const float*)d_in[4];
    const float* W3 = (const float*)d_in[5];
    const float* b3 = (const float*)d_in[6];
    float* out = (float*)d_out;

    unsigned short* h2  = (unsigned short*)d_ws;                 // 8*256*256*64 bf16
    unsigned short* W2r = h2 + (size_t)BATCH * HW * HW * C;      // 36864 elems
    unsigned short* W3r = W2r + (size_t)36 * 2 * C * 8;          // 110592 elems

    repack_w_kernel<<<576, 256, 0, stream>>>(W2, W3, W2r, W3r);
    conv2_fused_kernel<<<dim3(4, 64, 8), 256, 0, stream>>>(x, W1, b1, W2r, b2, h2);
    conv3_mfma_kernel<<<dim3(4, 61, 8), 512, 0, stream>>>(x, h2, W3r, b3, out);
}